// Round 7
// baseline (580.433 us; speedup 1.0000x reference)
//
#include <hip/hip_runtime.h>
#include <hip/hip_bf16.h>

#define N 8192
#define OD 64
#define E_EDGES 262144

#define BM 64
#define KSPLIT 16
#define KS_PER_SPLIT (N / KSPLIT)   // 512
#define SCAT_BLOCKS 8192

typedef __attribute__((ext_vector_type(8))) short bf16x8;
typedef __attribute__((ext_vector_type(4))) float f32x4;

__device__ __forceinline__ unsigned short f2bf(float f) {
    union { float f; unsigned u; } v; v.f = f;
    unsigned r = (v.u + 0x7fffu + ((v.u >> 16) & 1u)) >> 16;  // RNE
    return (unsigned short)r;
}

// ---- K1: W [N][OD] f32 -> wt [OD][N] bf16 (LDS transpose) + zero y/out/acc/ticket ----
__global__ __launch_bounds__(256) void prep_kernel(const float* __restrict__ w,
                                                   unsigned short* __restrict__ wt,
                                                   float4* __restrict__ y4,
                                                   float4* __restrict__ out4,
                                                   float* __restrict__ norm_acc,
                                                   unsigned int* __restrict__ ticket) {
    const int bid = blockIdx.x, t = threadIdx.x;   // 128 blocks x 256 thr
    const int base = bid * 256 + t;
    float4 z{0.f, 0.f, 0.f, 0.f};
    #pragma unroll
    for (int u = 0; u < 4; ++u) y4[base + u * 32768] = z;    // 131072 f4
    #pragma unroll
    for (int u = 0; u < 4; ++u) out4[base + u * 32768] = z;  // 131072 f4
    if (base == 0) { *norm_acc = 0.f; *ticket = 0u; }

    __shared__ unsigned short lds[64][80];
    const int kb = bid * 64;
    #pragma unroll
    for (int p = 0; p < 4; ++p) {
        int idx = p * 1024 + t * 4;
        int r = idx >> 6, c = idx & 63;     // r = local k, c = col
        float4 v = *(const float4*)(&w[(size_t)(kb + r) * OD + c]);
        lds[c + 0][r] = f2bf(v.x);
        lds[c + 1][r] = f2bf(v.y);
        lds[c + 2][r] = f2bf(v.z);
        lds[c + 3][r] = f2bf(v.w);
    }
    __syncthreads();
    const int colx = t >> 2, j0 = (t & 3) * 16;
    #pragma unroll
    for (int u = 0; u < 2; ++u) {
        *(bf16x8*)(wt + (size_t)colx * N + kb + j0 + u * 8) =
            *(const bf16x8*)(&lds[colx][j0 + u * 8]);
    }
}

// ---- K2: y += x[:,split] @ W[split,:] — register-only MFMA, split-K atomics ----
__global__ __launch_bounds__(256) void gemm_kernel(const float* __restrict__ x,
                                                   const unsigned short* __restrict__ wt,
                                                   float* __restrict__ y) {
    const int tid = threadIdx.x;
    const int wv = tid >> 6;
    const int lane = tid & 63;
    const int lrow = lane & 15;   // A-row / B-col within 16x16 fragment
    const int g = lane >> 4;      // k-group (8 elems)
    const int row = blockIdx.x * BM + wv * 16 + lrow;
    const int k0 = blockIdx.y * KS_PER_SPLIT;

    f32x4 acc[4] = {f32x4{0,0,0,0}, f32x4{0,0,0,0}, f32x4{0,0,0,0}, f32x4{0,0,0,0}};
    const float* xp = x + (size_t)row * N + k0 + g * 8;
    const unsigned short* wp = wt + k0 + g * 8;

    #pragma unroll 8
    for (int ks = 0; ks < KS_PER_SPLIT / 32; ++ks) {   // 16 iters
        float4 v0 = *(const float4*)(xp + ks * 32);
        float4 v1 = *(const float4*)(xp + ks * 32 + 4);
        bf16x8 a;
        a[0] = f2bf(v0.x); a[1] = f2bf(v0.y); a[2] = f2bf(v0.z); a[3] = f2bf(v0.w);
        a[4] = f2bf(v1.x); a[5] = f2bf(v1.y); a[6] = f2bf(v1.z); a[7] = f2bf(v1.w);
        #pragma unroll
        for (int cf = 0; cf < 4; ++cf) {
            bf16x8 b = *(const bf16x8*)(wp + (size_t)(cf * 16 + lrow) * N + ks * 32);
            acc[cf] = __builtin_amdgcn_mfma_f32_16x16x32_bf16(a, b, acc[cf], 0, 0, 0);
        }
    }
    // C/D layout: col = lane&15, row = (lane>>4)*4 + i (verified)
    float* yp = y + ((size_t)blockIdx.x * BM + wv * 16 + g * 4) * OD;
    #pragma unroll
    for (int cf = 0; cf < 4; ++cf) {
        #pragma unroll
        for (int i = 0; i < 4; ++i)
            atomicAdd(&yp[i * OD + cf * 16 + lrow], acc[cf][i]);
    }
}

// ---- K3: fused edge-scatter (latency-bound) + norm (HBM-bound) + ticket finalize ----
__device__ __forceinline__ void do_scatter(const float* __restrict__ values,
                                           const float* __restrict__ attn,
                                           const int* __restrict__ row,
                                           const int* __restrict__ col,
                                           const float* __restrict__ y,
                                           float* __restrict__ out,
                                           int bid, int t) {
    const int lane = t & 63;
    int e = bid * 4 + (t >> 6);            // 32768 waves, stride 32768
    #pragma unroll
    for (int it = 0; it < E_EDGES / (SCAT_BLOCKS * 4); ++it, e += SCAT_BLOCKS * 4) {
        const int r = row[e];
        const int c = col[e];
        const float ev = values[e] * attn[(size_t)r * N + c];
        atomicAdd(&out[r * OD + lane], ev * y[c * OD + lane]);
    }
}

__device__ __forceinline__ float do_norm_part(const float* __restrict__ attn, int bid, int t) {
    const float4* a4 = (const float4*)attn;
    float s = 0.f;
    int i = bid * 256 + t;                 // 2,097,152 threads, 8 f4 each
    #pragma unroll
    for (int u = 0; u < 8; ++u) {
        float4 v = a4[i + u * (SCAT_BLOCKS * 256)];
        s += v.x * v.x + v.y * v.y + v.z * v.z + v.w * v.w;
    }
    return s;
}

__global__ __launch_bounds__(256) void scatter_norm_kernel(
        const float* __restrict__ values, const float* __restrict__ attn,
        const int* __restrict__ row, const int* __restrict__ col,
        const float* __restrict__ y, float* __restrict__ out,
        float* __restrict__ norm_acc, unsigned int* __restrict__ ticket,
        float* __restrict__ out_norm) {
    const int bid = blockIdx.x, t = threadIdx.x;
    float s;
    if (bid & 1) {   // parity ordering: instant resource mixing among resident blocks
        s = do_norm_part(attn, bid, t);
        do_scatter(values, attn, row, col, y, out, bid, t);
    } else {
        do_scatter(values, attn, row, col, y, out, bid, t);
        s = do_norm_part(attn, bid, t);
    }
    // block-reduce norm partial
    for (int off = 32; off > 0; off >>= 1) s += __shfl_down(s, off, 64);
    __shared__ float wpart[4];
    int wid = t >> 6;
    if ((t & 63) == 0) wpart[wid] = s;
    __syncthreads();
    if (t == 0) {
        atomicAdd(norm_acc, wpart[0] + wpart[1] + wpart[2] + wpart[3]);
        __threadfence();
        unsigned int old = atomicAdd(ticket, 1u);
        if (old == SCAT_BLOCKS - 1) {
            *out_norm = sqrtf(*(volatile float*)norm_acc);
        }
    }
}

extern "C" void kernel_launch(void* const* d_in, const int* in_sizes, int n_in,
                              void* d_out, int out_size, void* d_ws, size_t ws_size,
                              hipStream_t stream) {
    const float* x      = (const float*)d_in[0];
    const float* attn   = (const float*)d_in[1];
    const float* weight = (const float*)d_in[2];
    const float* values = (const float*)d_in[3];
    const int*   row    = (const int*)d_in[4];
    const int*   col    = (const int*)d_in[5];
    float* out = (float*)d_out;

    char* wsb = (char*)d_ws;
    float*          norm_acc = (float*)wsb;                          // 4 B
    unsigned int*   ticket   = (unsigned int*)(wsb + 64);            // 4 B
    unsigned short* wt       = (unsigned short*)(wsb + (1u << 20));  // 1 MB
    float*          y        = (float*)(wsb + (2u << 20));           // 2 MB
    float*          out_norm = out + (size_t)N * OD;

    prep_kernel<<<128, 256, 0, stream>>>(weight, wt, (float4*)y, (float4*)out,
                                         norm_acc, ticket);
    gemm_kernel<<<dim3(N / BM, KSPLIT), 256, 0, stream>>>(x, wt, y);
    scatter_norm_kernel<<<SCAT_BLOCKS, 256, 0, stream>>>(values, attn, row, col, y, out,
                                                         norm_acc, ticket, out_norm);
}

// Round 8
// 182.236 us; speedup vs baseline: 3.1851x; 3.1851x over previous
//
#include <hip/hip_runtime.h>
#include <hip/hip_bf16.h>

#define N 8192
#define OD 64
#define E_EDGES 262144

#define BM 64
#define BK 64
#define KSPLIT 16
#define KS_PER_SPLIT (N / KSPLIT)    // 512
#define NTILES (KS_PER_SPLIT / BK)   // 8
#define NORM_BLOCKS 2048
#define SCAT_BLOCKS 8192

typedef __attribute__((ext_vector_type(8))) short bf16x8;
typedef __attribute__((ext_vector_type(4))) float f32x4;

__device__ __forceinline__ unsigned short f2bf(float f) {
    union { float f; unsigned u; } v; v.f = f;
    unsigned r = (v.u + 0x7fffu + ((v.u >> 16) & 1u)) >> 16;  // RNE
    return (unsigned short)r;
}

__device__ __forceinline__ void gload16(const void* g, void* l) {
    __builtin_amdgcn_global_load_lds(
        (const __attribute__((address_space(1))) unsigned int*)g,
        (__attribute__((address_space(3))) unsigned int*)l, 16, 0, 0);
}

// ---- K1: norm partials + W transpose-convert + zero y/out (R5-proven) ----
__global__ __launch_bounds__(256) void prep_kernel(const float* __restrict__ attn,
                                                   const float* __restrict__ w,
                                                   unsigned short* __restrict__ wt,
                                                   float4* __restrict__ y4,
                                                   float4* __restrict__ out4,
                                                   float* __restrict__ part) {
    const int bid = blockIdx.x, t = threadIdx.x;

    if (t < 128) {                       // zero y (131072 f4) + out (131072 f4)
        int zi = bid * 128 + t;
        float4 z{0.f, 0.f, 0.f, 0.f};
        if (zi < 131072) y4[zi] = z;
        else out4[zi - 131072] = z;
    }

    if (bid < 128) {                     // W [N][OD] -> wt [OD][N] bf16
        __shared__ unsigned short lds[64][80];
        const int kb = bid * 64;
        #pragma unroll
        for (int p = 0; p < 4; ++p) {
            int idx = p * 1024 + t * 4;
            int r = idx >> 6, c = idx & 63;
            float4 v = *(const float4*)(&w[(size_t)(kb + r) * OD + c]);
            lds[c + 0][r] = f2bf(v.x);
            lds[c + 1][r] = f2bf(v.y);
            lds[c + 2][r] = f2bf(v.z);
            lds[c + 3][r] = f2bf(v.w);
        }
        __syncthreads();
        const int colx = t >> 2, j0 = (t & 3) * 16;
        #pragma unroll
        for (int u = 0; u < 2; ++u) {
            *(bf16x8*)(wt + (size_t)colx * N + kb + j0 + u * 8) =
                *(const bf16x8*)(&lds[colx][j0 + u * 8]);
        }
    }

    const float4* a4 = (const float4*)attn;   // norm partial (grid-stride)
    const int total = (N * (long)N) / 4;
    float s = 0.f;
    for (long i = (long)bid * 256 + t; i < total; i += (long)NORM_BLOCKS * 256) {
        float4 v = a4[i];
        s += v.x * v.x + v.y * v.y + v.z * v.z + v.w * v.w;
    }
    for (int off = 32; off > 0; off >>= 1) s += __shfl_down(s, off, 64);
    __shared__ float wpart[4];
    int wid = t >> 6;
    if ((t & 63) == 0) wpart[wid] = s;
    __syncthreads();
    if (t == 0) part[bid] = wpart[0] + wpart[1] + wpart[2] + wpart[3];  // distinct addr, NO atomics
}

// ---- K2: y += x[:,split] @ W[split,:] — global_load_lds double-buffered MFMA ----
__global__ __launch_bounds__(256) void gemm_kernel(const float* __restrict__ x,
                                                   const unsigned short* __restrict__ wt,
                                                   float* __restrict__ y) {
    __shared__ float xs[2][BM * BK];            // 2 x 16 KB, 16B-chunk-swizzled rows
    __shared__ unsigned short bs[2][BM * BK];   // 2 x 8 KB

    const int t = threadIdx.x;
    const int wv = t >> 6, lane = t & 63;
    const int lrow = lane & 15, g = lane >> 4;
    const int sw = lrow & 7;                    // read-side swizzle key
    const int row0 = blockIdx.x * BM;
    const int k0 = blockIdx.y * KS_PER_SPLIT;

    const int xrow_b = t >> 4, xchunk = t & 15; // staging geometry
    const int brow_b = t >> 3, bchunk = t & 7;

    f32x4 acc[4] = {f32x4{0,0,0,0}, f32x4{0,0,0,0}, f32x4{0,0,0,0}, f32x4{0,0,0,0}};

    // STAGE: LDS dest linear (gload_lds requirement); SOURCE pre-swizzled by the
    // same XOR the reader applies (both-sides-or-neither, rule #21).
    #define STAGE(buf, tile)                                                          \
        {                                                                             \
            const int kk = k0 + (tile) * BK;                                          \
            _Pragma("unroll")                                                         \
            for (int j = 0; j < 4; ++j) {                                             \
                int r = j * 16 + xrow_b;                                              \
                gload16(&x[(size_t)(row0 + r) * N + kk + ((xchunk ^ (r & 7)) << 2)],  \
                        &xs[buf][j * 1024 + t * 4]);                                  \
            }                                                                         \
            _Pragma("unroll")                                                         \
            for (int j = 0; j < 2; ++j) {                                             \
                int r = j * 32 + brow_b;                                              \
                gload16(&wt[(size_t)r * N + kk + ((bchunk ^ (r & 7)) << 3)],          \
                        &bs[buf][j * 2048 + t * 8]);                                  \
            }                                                                         \
        }

    STAGE(0, 0);
    asm volatile("s_waitcnt vmcnt(0)" ::: "memory");
    __syncthreads();

    int cur = 0;
    for (int tile = 0; tile < NTILES; ++tile) {
        if (tile + 1 < NTILES) STAGE(cur ^ 1, tile + 1);   // prefetch stays in flight
        const int ar = wv * 16 + lrow;
        #pragma unroll
        for (int ks = 0; ks < 2; ++ks) {
            const int c0 = ks * 8 + g * 2;
            float4 lo = *(const float4*)&xs[cur][ar * 64 + ((c0 ^ sw) << 2)];
            float4 hi = *(const float4*)&xs[cur][ar * 64 + (((c0 + 1) ^ sw) << 2)];
            bf16x8 a;
            a[0] = f2bf(lo.x); a[1] = f2bf(lo.y); a[2] = f2bf(lo.z); a[3] = f2bf(lo.w);
            a[4] = f2bf(hi.x); a[5] = f2bf(hi.y); a[6] = f2bf(hi.z); a[7] = f2bf(hi.w);
            #pragma unroll
            for (int cf = 0; cf < 4; ++cf) {
                const int rb = cf * 16 + lrow;
                bf16x8 b = *(const bf16x8*)&bs[cur][rb * 64 + (((ks * 4 + g) ^ sw) << 3)];
                acc[cf] = __builtin_amdgcn_mfma_f32_16x16x32_bf16(a, b, acc[cf], 0, 0, 0);
            }
        }
        asm volatile("s_waitcnt vmcnt(0)" ::: "memory");
        __syncthreads();
        cur ^= 1;
    }

    // C/D layout: col = lane&15, row = (lane>>4)*4 + i (verified); split-K via atomics
    float* yp = y + ((size_t)row0 + wv * 16 + g * 4) * OD;
    #pragma unroll
    for (int cf = 0; cf < 4; ++cf) {
        #pragma unroll
        for (int i = 0; i < 4; ++i)
            atomicAdd(&yp[i * OD + cf * 16 + lrow], acc[cf][i]);
    }
    #undef STAGE
}

// ---- K3: edge scatter (R5-proven) + norm finalize in one extra block ----
__global__ __launch_bounds__(256) void scatter_kernel(const float* __restrict__ values,
                                                      const float* __restrict__ attn,
                                                      const int* __restrict__ row,
                                                      const int* __restrict__ col,
                                                      const float* __restrict__ y,
                                                      float* __restrict__ out,
                                                      const float* __restrict__ part,
                                                      float* __restrict__ out_norm) {
    if (blockIdx.x == SCAT_BLOCKS) {   // norm finalize (single block, plain reads)
        float s = 0.f;
        #pragma unroll
        for (int k = 0; k < NORM_BLOCKS / 256; ++k) s += part[k * 256 + threadIdx.x];
        for (int off = 32; off > 0; off >>= 1) s += __shfl_down(s, off, 64);
        __shared__ float wp[4];
        int wid = threadIdx.x >> 6;
        if ((threadIdx.x & 63) == 0) wp[wid] = s;
        __syncthreads();
        if (threadIdx.x == 0) *out_norm = sqrtf(wp[0] + wp[1] + wp[2] + wp[3]);
        return;
    }
    const int lane = threadIdx.x & 63;
    int e = blockIdx.x * 4 + (threadIdx.x >> 6);
    #pragma unroll
    for (int it = 0; it < E_EDGES / (SCAT_BLOCKS * 4); ++it, e += SCAT_BLOCKS * 4) {
        const int r = row[e];
        const int c = col[e];
        const float ev = values[e] * attn[(size_t)r * N + c];
        atomicAdd(&out[r * OD + lane], ev * y[c * OD + lane]);
    }
}

extern "C" void kernel_launch(void* const* d_in, const int* in_sizes, int n_in,
                              void* d_out, int out_size, void* d_ws, size_t ws_size,
                              hipStream_t stream) {
    const float* x      = (const float*)d_in[0];
    const float* attn   = (const float*)d_in[1];
    const float* weight = (const float*)d_in[2];
    const float* values = (const float*)d_in[3];
    const int*   row    = (const int*)d_in[4];
    const int*   col    = (const int*)d_in[5];
    float* out = (float*)d_out;

    char* wsb = (char*)d_ws;
    float*          part = (float*)wsb;                          // 8 KB (2048 f32)
    unsigned short* wt   = (unsigned short*)(wsb + (1u << 20));  // 1 MB
    float*          y    = (float*)(wsb + (2u << 20));           // 2 MB

    prep_kernel<<<NORM_BLOCKS, 256, 0, stream>>>(attn, weight, wt, (float4*)y,
                                                 (float4*)out, part);
    gemm_kernel<<<dim3(N / BM, KSPLIT), 256, 0, stream>>>(x, wt, y);
    scatter_kernel<<<SCAT_BLOCKS + 1, 256, 0, stream>>>(values, attn, row, col, y, out,
                                                        part, out + (size_t)N * OD);
}

// Round 9
// 164.676 us; speedup vs baseline: 3.5247x; 1.1066x over previous
//
#include <hip/hip_runtime.h>
#include <hip/hip_bf16.h>

#define N 8192
#define OD 64
#define E_EDGES 262144

#define BM 64
#define BK 64
#define KSPLIT 16
#define KS_PER_SPLIT (N / KSPLIT)    // 512
#define NTILES (KS_PER_SPLIT / BK)   // 8
#define SCAT_BLOCKS 8192
#define EDGE_ITERS (E_EDGES / (SCAT_BLOCKS * 4))   // 8

typedef __attribute__((ext_vector_type(8))) short bf16x8;
typedef __attribute__((ext_vector_type(4))) float f32x4;

__device__ __forceinline__ unsigned short f2bf(float f) {
    union { float f; unsigned u; } v; v.f = f;
    unsigned r = (v.u + 0x7fffu + ((v.u >> 16) & 1u)) >> 16;  // RNE
    return (unsigned short)r;
}

__device__ __forceinline__ void gload16(const void* g, void* l) {
    __builtin_amdgcn_global_load_lds(
        (const __attribute__((address_space(1))) unsigned int*)g,
        (__attribute__((address_space(3))) unsigned int*)l, 16, 0, 0);
}

// ---- K1 (tiny): W [N][OD] f32 -> wt [OD][N] bf16 + zero y/out ----
__global__ __launch_bounds__(256) void prep_kernel(const float* __restrict__ w,
                                                   unsigned short* __restrict__ wt,
                                                   float4* __restrict__ y4,
                                                   float4* __restrict__ out4) {
    const int bid = blockIdx.x, t = threadIdx.x;   // 128 blocks
    const int base = bid * 256 + t;                // [0, 32768)
    float4 z{0.f, 0.f, 0.f, 0.f};
    #pragma unroll
    for (int u = 0; u < 4; ++u) y4[base + u * 32768] = z;    // 131072 f4 (2 MB)
    #pragma unroll
    for (int u = 0; u < 4; ++u) out4[base + u * 32768] = z;  // 131072 f4 (2 MB)

    __shared__ unsigned short lds[64][80];
    const int kb = bid * 64;
    #pragma unroll
    for (int p = 0; p < 4; ++p) {
        int idx = p * 1024 + t * 4;
        int r = idx >> 6, c = idx & 63;     // r = local k, c = col
        float4 v = *(const float4*)(&w[(size_t)(kb + r) * OD + c]);
        lds[c + 0][r] = f2bf(v.x);
        lds[c + 1][r] = f2bf(v.y);
        lds[c + 2][r] = f2bf(v.z);
        lds[c + 3][r] = f2bf(v.w);
    }
    __syncthreads();
    const int colx = t >> 2, j0 = (t & 3) * 16;
    #pragma unroll
    for (int u = 0; u < 2; ++u) {
        *(bf16x8*)(wt + (size_t)colx * N + kb + j0 + u * 8) =
            *(const bf16x8*)(&lds[colx][j0 + u * 8]);
    }
}

// ---- K2: y += x[:,split] @ W[split,:] — global_load_lds double-buffered MFMA (R8) ----
__global__ __launch_bounds__(256) void gemm_kernel(const float* __restrict__ x,
                                                   const unsigned short* __restrict__ wt,
                                                   float* __restrict__ y) {
    __shared__ float xs[2][BM * BK];            // 2 x 16 KB, 16B-chunk-swizzled rows
    __shared__ unsigned short bs[2][BM * BK];   // 2 x 8 KB

    const int t = threadIdx.x;
    const int wv = t >> 6, lane = t & 63;
    const int lrow = lane & 15, g = lane >> 4;
    const int sw = lrow & 7;                    // read-side swizzle key
    const int row0 = blockIdx.x * BM;
    const int k0 = blockIdx.y * KS_PER_SPLIT;

    const int xrow_b = t >> 4, xchunk = t & 15; // staging geometry
    const int brow_b = t >> 3, bchunk = t & 7;

    f32x4 acc[4] = {f32x4{0,0,0,0}, f32x4{0,0,0,0}, f32x4{0,0,0,0}, f32x4{0,0,0,0}};

    // LDS dest linear (gload_lds rule); SOURCE pre-swizzled with the reader's XOR (rule #21).
    #define STAGE(buf, tile)                                                          \
        {                                                                             \
            const int kk = k0 + (tile) * BK;                                          \
            _Pragma("unroll")                                                         \
            for (int j = 0; j < 4; ++j) {                                             \
                int r = j * 16 + xrow_b;                                              \
                gload16(&x[(size_t)(row0 + r) * N + kk + ((xchunk ^ (r & 7)) << 2)],  \
                        &xs[buf][j * 1024 + t * 4]);                                  \
            }                                                                         \
            _Pragma("unroll")                                                         \
            for (int j = 0; j < 2; ++j) {                                             \
                int r = j * 32 + brow_b;                                              \
                gload16(&wt[(size_t)r * N + kk + ((bchunk ^ (r & 7)) << 3)],          \
                        &bs[buf][j * 2048 + t * 8]);                                  \
            }                                                                         \
        }

    STAGE(0, 0);
    asm volatile("s_waitcnt vmcnt(0)" ::: "memory");
    __syncthreads();

    int cur = 0;
    for (int tile = 0; tile < NTILES; ++tile) {
        if (tile + 1 < NTILES) STAGE(cur ^ 1, tile + 1);   // prefetch stays in flight
        const int ar = wv * 16 + lrow;
        #pragma unroll
        for (int ks = 0; ks < 2; ++ks) {
            const int c0 = ks * 8 + g * 2;
            float4 lo = *(const float4*)&xs[cur][ar * 64 + ((c0 ^ sw) << 2)];
            float4 hi = *(const float4*)&xs[cur][ar * 64 + (((c0 + 1) ^ sw) << 2)];
            bf16x8 a;
            a[0] = f2bf(lo.x); a[1] = f2bf(lo.y); a[2] = f2bf(lo.z); a[3] = f2bf(lo.w);
            a[4] = f2bf(hi.x); a[5] = f2bf(hi.y); a[6] = f2bf(hi.z); a[7] = f2bf(hi.w);
            #pragma unroll
            for (int cf = 0; cf < 4; ++cf) {
                const int rb = cf * 16 + lrow;
                bf16x8 b = *(const bf16x8*)&bs[cur][rb * 64 + (((ks * 4 + g) ^ sw) << 3)];
                acc[cf] = __builtin_amdgcn_mfma_f32_16x16x32_bf16(a, b, acc[cf], 0, 0, 0);
            }
        }
        asm volatile("s_waitcnt vmcnt(0)" ::: "memory");
        __syncthreads();
        cur ^= 1;
    }

    // C/D layout: col = lane&15, row = (lane>>4)*4 + i (verified); split-K via atomics
    float* yp = y + ((size_t)row0 + wv * 16 + g * 4) * OD;
    #pragma unroll
    for (int cf = 0; cf < 4; ++cf) {
        #pragma unroll
        for (int i = 0; i < 4; ++i)
            atomicAdd(&yp[i * OD + cf * 16 + lrow], acc[cf][i]);
    }
    #undef STAGE
}

// ---- K3: fused scatter (latency-bound, batched) + norm stream (HBM-bound) ----
__device__ __forceinline__ void do_scatter(const float* __restrict__ values,
                                           const float* __restrict__ attn,
                                           const int* __restrict__ row,
                                           const int* __restrict__ col,
                                           const float* __restrict__ y,
                                           float* __restrict__ out,
                                           int bid, int t) {
    const int lane = t & 63;
    const int w = t >> 6;
    int r8[EDGE_ITERS], c8[EDGE_ITERS];
    float v8[EDGE_ITERS], a8[EDGE_ITERS];
    #pragma unroll
    for (int i = 0; i < EDGE_ITERS; ++i) {       // phase 1: edge meta (independent)
        int e = bid * 4 + w + i * (SCAT_BLOCKS * 4);
        r8[i] = row[e]; c8[i] = col[e]; v8[i] = values[e];
    }
    #pragma unroll
    for (int i = 0; i < EDGE_ITERS; ++i)         // phase 2: 8 gathers in flight
        a8[i] = attn[(size_t)r8[i] * N + c8[i]];
    #pragma unroll
    for (int i = 0; i < EDGE_ITERS; ++i) {       // phase 3: y read (L2) + atomic
        float yv = y[c8[i] * OD + lane];
        atomicAdd(&out[r8[i] * OD + lane], v8[i] * a8[i] * yv);
    }
}

__device__ __forceinline__ float do_norm_part(const float* __restrict__ attn, int bid, int t) {
    const float4* a4 = (const float4*)attn;
    float s = 0.f;
    int i = bid * 256 + t;                       // 8 independent f4 loads per thread
    #pragma unroll
    for (int u = 0; u < 8; ++u) {
        float4 v = a4[i + u * (SCAT_BLOCKS * 256)];
        s += v.x * v.x + v.y * v.y + v.z * v.z + v.w * v.w;
    }
    return s;
}

__global__ __launch_bounds__(256) void scatter_norm_kernel(
        const float* __restrict__ values, const float* __restrict__ attn,
        const int* __restrict__ row, const int* __restrict__ col,
        const float* __restrict__ y, float* __restrict__ out,
        float* __restrict__ part) {
    const int bid = blockIdx.x, t = threadIdx.x;
    float s;
    if (bid & 1) {   // parity: resident blocks mix the two resource profiles
        s = do_norm_part(attn, bid, t);
        do_scatter(values, attn, row, col, y, out, bid, t);
    } else {
        do_scatter(values, attn, row, col, y, out, bid, t);
        s = do_norm_part(attn, bid, t);
    }
    for (int off = 32; off > 0; off >>= 1) s += __shfl_down(s, off, 64);
    __shared__ float wpart[4];
    int wid = t >> 6;
    if ((t & 63) == 0) wpart[wid] = s;
    __syncthreads();
    if (t == 0) part[bid] = wpart[0] + wpart[1] + wpart[2] + wpart[3];  // plain store
}

// ---- K4 (tiny): norm = sqrt(sum of 8192 partials) ----
__global__ __launch_bounds__(256) void finalize_kernel(const float* __restrict__ part,
                                                       float* __restrict__ out_norm) {
    float s = 0.f;
    #pragma unroll
    for (int k = 0; k < SCAT_BLOCKS / 256; ++k) s += part[k * 256 + threadIdx.x];
    for (int off = 32; off > 0; off >>= 1) s += __shfl_down(s, off, 64);
    __shared__ float wp[4];
    int wid = threadIdx.x >> 6;
    if ((threadIdx.x & 63) == 0) wp[wid] = s;
    __syncthreads();
    if (threadIdx.x == 0) *out_norm = sqrtf(wp[0] + wp[1] + wp[2] + wp[3]);
}

extern "C" void kernel_launch(void* const* d_in, const int* in_sizes, int n_in,
                              void* d_out, int out_size, void* d_ws, size_t ws_size,
                              hipStream_t stream) {
    const float* x      = (const float*)d_in[0];
    const float* attn   = (const float*)d_in[1];
    const float* weight = (const float*)d_in[2];
    const float* values = (const float*)d_in[3];
    const int*   row    = (const int*)d_in[4];
    const int*   col    = (const int*)d_in[5];
    float* out = (float*)d_out;

    char* wsb = (char*)d_ws;
    float*          part = (float*)wsb;                          // 32 KB (8192 f32)
    unsigned short* wt   = (unsigned short*)(wsb + (1u << 20));  // 1 MB
    float*          y    = (float*)(wsb + (2u << 20));           // 2 MB

    prep_kernel<<<128, 256, 0, stream>>>(weight, wt, (float4*)y, (float4*)out);
    gemm_kernel<<<dim3(N / BM, KSPLIT), 256, 0, stream>>>(x, wt, y);
    scatter_norm_kernel<<<SCAT_BLOCKS, 256, 0, stream>>>(values, attn, row, col, y, out, part);
    finalize_kernel<<<1, 256, 0, stream>>>(part, out + (size_t)N * OD);
}